// Round 6
// baseline (679.934 us; speedup 1.0000x reference)
//
#include <hip/hip_runtime.h>
#include <hip/hip_bf16.h>
#include <stdint.h>

// QSCrossAttention: B=8, Nq=1024, Nkv=4096, D=512, fp32 I/O, bf16 MFMA compute.
// R14: residency experiment. Six staging structures (R8-R13) all measured
//      65-74us with every pipe ~90% idle and occupancy tracking the blocks/CU
//      cap linearly (3->14%, 4->18%) -> latency-dominated, TLP-starved.
//      This round: exact R9 2-barrier BK=32 loop, but LDS dieted 34.8->17.4KB
//      (epilogue repack sliced into two 64-row phases over Rt[64][136]) ->
//      9 blocks/CU LDS cap, __launch_bounds__(256,6). One variable: residency.

typedef __bf16 bf16;
typedef bf16 bf16x8 __attribute__((ext_vector_type(8)));
typedef bf16 bf16x4 __attribute__((ext_vector_type(4)));
typedef float f32x4 __attribute__((ext_vector_type(4)));

#define NB 8
#define NQ 1024
#define NKV 4096
#define DD 512
#define RT_LD 136  // repack leading dim (272B rows)

// Async global->LDS, 16B per lane. g per-lane global src; l WAVE-UNIFORM base.
__device__ __forceinline__ void lds16(const bf16* g, bf16* l) {
  __builtin_amdgcn_global_load_lds(
      (const __attribute__((address_space(1))) unsigned int*)g,
      (__attribute__((address_space(3))) unsigned int*)l, 16, 0, 0);
}

// ---- scan_mask: 3-mode sniff + denom zero + per-batch prefix scan ---------
__global__ void scan_mask(const void* __restrict__ mask,
                          int* __restrict__ idx, int* __restrict__ cnt,
                          int* __restrict__ kpad, float* __restrict__ denom) {
  const int b = blockIdx.x, tid = threadIdx.x;
  for (int i = tid; i < NQ; i += 256) denom[b * NQ + i] = 0.f;

  __shared__ int s0, s1;
  if (tid == 0) { s0 = 0; s1 = 0; }
  __syncthreads();
  {
    const unsigned* mw = (const unsigned*)mask;
    int b0 = 0, b1 = 0;
    for (int i = tid; i < 8192; i += 256) {
      unsigned v = mw[i];
      if (v > 1u) b0 = 1;
      if (v != 0u && v != 0x3F800000u) b1 = 1;
    }
    if (b0) atomicOr(&s0, 1);
    if (b1) atomicOr(&s1, 1);
  }
  __syncthreads();
  const int mode = (s0 == 0) ? 0 : ((s1 == 0) ? 1 : 2);

  __shared__ int ps[256];
  unsigned bits = 0;
  int c = 0;
  const int base = tid * 16;
  for (int i = 0; i < 16; ++i) {
    const int col = base + i;
    bool k;
    if (mode == 0)      k = ((const int*)mask)[b * NKV + col] != 0;
    else if (mode == 1) k = ((const float*)mask)[b * NKV + col] != 0.f;
    else                k = ((const unsigned char*)mask)[b * NKV + col] != 0;
    bits |= (unsigned)k << i;
    c += k;
  }
  ps[tid] = c;
  __syncthreads();
  for (int s = 1; s < 256; s <<= 1) {
    int v = (tid >= s) ? ps[tid - s] : 0;
    __syncthreads();
    ps[tid] += v;
    __syncthreads();
  }
  int off = ps[tid] - c;
  for (int i = 0; i < 16; ++i)
    if ((bits >> i) & 1) idx[b * NKV + off++] = base + i;
  if (tid == 255) {
    cnt[b] = ps[255];
    kpad[b] = (ps[255] + 127) & ~127;
  }
}

// ---- prep: gather_qx (blk<2048) | cvt proto (<6144) | cvt weights ---------
__global__ void prep(const float* __restrict__ qx, const int* __restrict__ idx,
                     const int* __restrict__ cnt, const int* __restrict__ kpad,
                     bf16* __restrict__ qc,
                     const float* __restrict__ proto, bf16* __restrict__ proto_b,
                     const float* __restrict__ Wq, const float* __restrict__ Wk,
                     const float* __restrict__ Wv, const float* __restrict__ Wp,
                     bf16* __restrict__ Wq_b, bf16* __restrict__ Wkv_b,
                     bf16* __restrict__ Wp_b) {
  const int blk = blockIdx.x, tid = threadIdx.x;
  if (blk < 2048) {
    const int b = blk >> 8, bx = blk & 255;
    const int wave = tid >> 6, lane = tid & 63;
    const int r0 = bx * 16 + wave * 4;
    const int n = cnt[b];
    const int kp = kpad[b];
#pragma unroll
    for (int j = 0; j < 4; ++j) {
      const int row = r0 + j;
      if (row >= kp) return;
      bf16x4* d = (bf16x4*)(qc + ((long)b * NKV + row) * DD) + lane;
      if (row < n) {
        const int src = idx[b * NKV + row];
        const float4* s = (const float4*)(qx + ((long)b * NKV + src) * DD) + lane;
        float4 v0 = s[0], v1 = s[64];
        bf16x4 o0, o1;
        o0.x = (bf16)v0.x; o0.y = (bf16)v0.y; o0.z = (bf16)v0.z; o0.w = (bf16)v0.w;
        o1.x = (bf16)v1.x; o1.y = (bf16)v1.y; o1.z = (bf16)v1.z; o1.w = (bf16)v1.w;
        d[0] = o0;
        d[64] = o1;
      } else {
        bf16x4 z;
        z.x = (bf16)0.f; z.y = (bf16)0.f; z.z = (bf16)0.f; z.w = (bf16)0.f;
        d[0] = z;
        d[64] = z;
      }
    }
  } else if (blk < 6144) {
    const int i = (blk - 2048) * 256 + tid;
    float4 v = ((const float4*)proto)[i];
    bf16x4 o;
    o.x = (bf16)v.x; o.y = (bf16)v.y; o.z = (bf16)v.z; o.w = (bf16)v.w;
    ((bf16x4*)proto_b)[i] = o;
  } else {
    const int j = (blk - 6144) * 256 + tid;
    const int w = j >> 16, r = j & 65535;
    const float* src = (w == 0) ? Wq : (w == 1) ? Wk : (w == 2) ? Wv : Wp;
    bf16x4* dst = (w == 0) ? (bf16x4*)Wq_b
                : (w == 3) ? (bf16x4*)Wp_b
                           : (bf16x4*)Wkv_b + (w == 2 ? 65536 : 0);
    float4 v = ((const float4*)src)[r];
    bf16x4 o;
    o.x = (bf16)v.x; o.y = (bf16)v.y; o.z = (bf16)v.z; o.w = (bf16)v.w;
    dst[r] = o;
  }
}

// -------- 128x128-tile GEMM, BK=32, 2-barrier, LDS-dieted epilogues --------
// LDS 17408B: stage A[0:4096]+B[4096:8192] elts; Rt overlay [64][RT_LD]=8704.
// EPI 0 = bf16 store (q-proj). EPI 2 = S: exp + zeroing + rowsum + P store.
// EPI 4 = f32 direct store (out-proj). EPI 5 = kv dual (k | vT transposed).
template <int EPI>
__global__ void __launch_bounds__(256, 6)
gemm_bt(const bf16* __restrict__ A, const bf16* __restrict__ Bw,
        void* __restrict__ Cp, void* __restrict__ Cp2,
        int N, int Klen, int Kstride,
        long sA, long sB, long sC,
        const int* __restrict__ cnt, const int* __restrict__ kpad,
        float* __restrict__ denom, float scale, int M) {
  __shared__ alignas(16) bf16 Smem[8704];  // 17408 B
  bf16* As = Smem;
  bf16* Bs = Smem + 4096;
  bf16* Rt = Smem;  // 64-row epilogue overlay
  const int tid = threadIdx.x;
  const int wave = tid >> 6, lane = tid & 63;
  const int l15 = lane & 15, l4 = lane >> 4;
  const int wm = (wave >> 1) * 64, wn = (wave & 1) * 64;
  const int bx = (EPI == 5) ? blockIdx.y : blockIdx.x;
  const int by = (EPI == 5) ? blockIdx.x : blockIdx.y;
  const int b = blockIdx.z;

  if constexpr (EPI == 2) {
    if (bx * 128 >= kpad[b]) return;
  } else if constexpr (EPI == 5) {
    const int bb = by >> 5, loc = (by & 31) * 128;
    if (loc >= kpad[bb]) return;
  }

  const bf16* Ab = A + (long)b * sA + (long)(by * 128) * Kstride;
  const bf16* Bb = Bw + (long)b * sB + (long)(bx * 128) * Kstride;

  const int c0 = wave * 2, c1 = wave * 2 + 1;
  const int srow = lane >> 2;
  const int scol = (lane & 3) * 8;
  const bf16* ag0 = Ab + (long)(c0 * 16 + srow) * Kstride + scol;
  const bf16* ag1 = Ab + (long)(c1 * 16 + srow) * Kstride + scol;
  const bf16* bg0 = Bb + (long)(c0 * 16 + srow) * Kstride + scol;
  const bf16* bg1 = Bb + (long)(c1 * 16 + srow) * Kstride + scol;
  bf16* al0 = As + c0 * 512;
  bf16* al1 = As + c1 * 512;
  bf16* bl0 = Bs + c0 * 512;
  bf16* bl1 = Bs + c1 * 512;

  f32x4 acc[4][4] = {};

  for (int kt = 0; kt < Klen; kt += 32) {
    __syncthreads();  // previous iteration's LDS readers done
    lds16(ag0, al0);
    lds16(ag1, al1);
    lds16(bg0, bl0);
    lds16(bg1, bl1);
    ag0 += 32; ag1 += 32; bg0 += 32; bg1 += 32;
    __syncthreads();  // vmcnt(0) drained before barrier -> tile ready
    bf16x8 af[4], bfr[4];
#pragma unroll
    for (int t = 0; t < 4; ++t)
      af[t] = *(const bf16x8*)(As + (wm + t * 16 + l15) * 32 + l4 * 8);
#pragma unroll
    for (int t = 0; t < 4; ++t)
      bfr[t] = *(const bf16x8*)(Bs + (wn + t * 16 + l15) * 32 + l4 * 8);
#pragma unroll
    for (int mt = 0; mt < 4; ++mt)
#pragma unroll
      for (int nt = 0; nt < 4; ++nt)
        acc[mt][nt] = __builtin_amdgcn_mfma_f32_16x16x32_bf16(af[mt], bfr[nt],
                                                              acc[mt][nt], 0, 0, 0);
  }

  const int rowBase = by * 128 + wm;
  const int colBase = bx * 128 + wn;
  const int tR = by * 128;
  const int tC = bx * 128;
  const int r0 = tid >> 2, cq = (tid & 3) * 32;  // store helpers (r0 in [0,64))

  __syncthreads();  // K-loop LDS dead before Rt overlay

  if constexpr (EPI == 2) {
    bf16* C = (bf16*)Cp + (long)b * sC;
    const int nkeep = cnt[b];
    // pass 1: rowsums (register-only)
    float rs[4][4];
#pragma unroll
    for (int mt = 0; mt < 4; ++mt)
#pragma unroll
      for (int r = 0; r < 4; ++r) rs[mt][r] = 0.f;
#pragma unroll
    for (int nt = 0; nt < 4; ++nt) {
      const bool keep = (colBase + nt * 16 + l15) < nkeep;
#pragma unroll
      for (int mt = 0; mt < 4; ++mt)
#pragma unroll
        for (int r = 0; r < 4; ++r)
          rs[mt][r] += keep ? __expf(acc[mt][nt][r] * scale) : 0.f;
    }
#pragma unroll
    for (int mt = 0; mt < 4; ++mt)
#pragma unroll
      for (int r = 0; r < 4; ++r) {
        float v = rs[mt][r];
        v += __shfl_xor(v, 1, 64);
        v += __shfl_xor(v, 2, 64);
        v += __shfl_xor(v, 4, 64);
        v += __shfl_xor(v, 8, 64);
        if (l15 == 0)
          atomicAdd(&denom[b * M + rowBase + mt * 16 + l4 * 4 + r], v);
      }
    // two 64-row phases: waves wm==0 then wm==64 repack into Rt[64][RT_LD]
#pragma unroll
    for (int ph = 0; ph < 2; ++ph) {
      if (wm == ph * 64) {
#pragma unroll
        for (int nt = 0; nt < 4; ++nt) {
          const bool keep = (colBase + nt * 16 + l15) < nkeep;
#pragma unroll
          for (int mt = 0; mt < 4; ++mt)
#pragma unroll
            for (int r = 0; r < 4; ++r) {
              float p = keep ? __expf(acc[mt][nt][r] * scale) : 0.f;
              Rt[(mt * 16 + l4 * 4 + r) * RT_LD + wn + nt * 16 + l15] = (bf16)p;
            }
        }
      }
      __syncthreads();
#pragma unroll
      for (int j = 0; j < 4; ++j) {
        bf16x8 v = *(const bf16x8*)(Rt + r0 * RT_LD + cq + j * 8);
        *(bf16x8*)(C + (long)(tR + ph * 64 + r0) * N + tC + cq + j * 8) = v;
      }
      __syncthreads();
    }
  } else if constexpr (EPI == 0) {
    bf16* C = (bf16*)Cp;
#pragma unroll
    for (int ph = 0; ph < 2; ++ph) {
      if (wm == ph * 64) {
#pragma unroll
        for (int mt = 0; mt < 4; ++mt)
#pragma unroll
          for (int nt = 0; nt < 4; ++nt)
#pragma unroll
            for (int r = 0; r < 4; ++r)
              Rt[(mt * 16 + l4 * 4 + r) * RT_LD + wn + nt * 16 + l15] =
                  (bf16)acc[mt][nt][r];
      }
      __syncthreads();
#pragma unroll
      for (int j = 0; j < 4; ++j) {
        bf16x8 v = *(const bf16x8*)(Rt + r0 * RT_LD + cq + j * 8);
        *(bf16x8*)(C + (long)(tR + ph * 64 + r0) * N + tC + cq + j * 8) = v;
      }
      __syncthreads();
    }
  } else if constexpr (EPI == 4) {
    float* C = (float*)Cp;
#pragma unroll
    for (int mt = 0; mt < 4; ++mt)
#pragma unroll
      for (int nt = 0; nt < 4; ++nt)
#pragma unroll
        for (int r = 0; r < 4; ++r)
          C[(long)(tR + wm + mt * 16 + l4 * 4 + r) * N + tC + wn + nt * 16 + l15] =
              acc[mt][nt][r];
  } else {  // EPI == 5: kv dual epilogue
    if (tC < 512) {
      bf16* C = (bf16*)Cp;  // k: [B*NKV][512]
#pragma unroll
      for (int ph = 0; ph < 2; ++ph) {
        if (wm == ph * 64) {
#pragma unroll
          for (int mt = 0; mt < 4; ++mt)
#pragma unroll
            for (int nt = 0; nt < 4; ++nt)
#pragma unroll
              for (int r = 0; r < 4; ++r)
                Rt[(mt * 16 + l4 * 4 + r) * RT_LD + wn + nt * 16 + l15] =
                    (bf16)acc[mt][nt][r];
        }
        __syncthreads();
#pragma unroll
        for (int j = 0; j < 4; ++j) {
          bf16x8 v = *(const bf16x8*)(Rt + r0 * RT_LD + cq + j * 8);
          *(bf16x8*)(C + (long)(tR + ph * 64 + r0) * 512 + tC + cq + j * 8) = v;
        }
        __syncthreads();
      }
    } else {
      bf16* C = (bf16*)Cp2;  // vT: [B][512][NKV], transpose via Rt[d_loc][kv]
      const int bb = tR >> 12, kvloc = tR & 4095;
#pragma unroll
      for (int ph = 0; ph < 2; ++ph) {
        // phase ph: columns (d) [ph*64, ph*64+64) -> waves with wn == ph*64
        if (wn == ph * 64) {
#pragma unroll
          for (int mt = 0; mt < 4; ++mt) {
            const int rr = wm + mt * 16 + l4 * 4;
#pragma unroll
            for (int nt = 0; nt < 4; ++nt) {
              const int cloc = nt * 16 + l15;  // 0..63 within phase
              bf16x4 o;
              o.x = (bf16)acc[mt][nt][0]; o.y = (bf16)acc[mt][nt][1];
              o.z = (bf16)acc[mt][nt][2]; o.w = (bf16)acc[mt][nt][3];
              *(bf16x4*)(Rt + cloc * RT_LD + rr) = o;
            }
          }
        }
        __syncthreads();
#pragma unroll
        for (int j = 0; j < 4; ++j) {
          bf16x8 v = *(const bf16x8*)(Rt + r0 * RT_LD + cq + j * 8);
          *(bf16x8*)(C + (long)bb * DD * NKV +
                     (long)(tC - 512 + ph * 64 + r0) * NKV + kvloc + cq + j * 8) = v;
        }
        __syncthreads();
      }
    }
  }
}

// ---- PV direct: x = (P @ vT^T)/denom, BK=32, 2-barrier, dieted LDS --------
// Tile 64q x 128d, K = kpad[b]. Grid (16,4,8). LDS 17408B (stage 12KB | Rt).
__global__ void __launch_bounds__(256, 6)
pv_direct(const bf16* __restrict__ P, const bf16* __restrict__ vT,
          const float* __restrict__ denom, const int* __restrict__ kpad,
          bf16* __restrict__ x) {
  __shared__ alignas(16) bf16 Smem[8704];  // 17408 B
  bf16* As = Smem;
  bf16* Bs = Smem + 2048;
  bf16* Rt = Smem;  // 64-row overlay [64][RT_LD]
  const int tid = threadIdx.x;
  const int wave = tid >> 6, lane = tid & 63;
  const int l15 = lane & 15, l4 = lane >> 4;
  const int wm = (wave >> 1) * 32, wn = (wave & 1) * 64;
  const int qB = blockIdx.x * 64;
  const int dB = blockIdx.y * 128;
  const int b = blockIdx.z;
  const int Kb = kpad[b];

  const bf16* Ab = P + (long)b * NQ * NKV + (long)qB * NKV;
  const bf16* Bb = vT + (long)b * DD * NKV + (long)dB * NKV;

  const int srow = lane >> 2, scol = (lane & 3) * 8;
  const int c0 = wave * 2, c1 = wave * 2 + 1;
  const bf16* ag  = Ab + (long)(wave * 16 + srow) * NKV + scol;
  const bf16* bg0 = Bb + (long)(c0 * 16 + srow) * NKV + scol;
  const bf16* bg1 = Bb + (long)(c1 * 16 + srow) * NKV + scol;
  bf16* la  = As + wave * 512;
  bf16* lb0 = Bs + c0 * 512;
  bf16* lb1 = Bs + c1 * 512;

  f32x4 acc[2][4] = {};

  for (int kt = 0; kt < Kb; kt += 32) {
    __syncthreads();
    lds16(ag, la);
    lds16(bg0, lb0);
    lds16(bg1, lb1);
    ag += 32; bg0 += 32; bg1 += 32;
    __syncthreads();
    bf16x8 af[2], bfr[4];
#pragma unroll
    for (int t = 0; t < 2; ++t)
      af[t] = *(const bf16x8*)(As + (wm + t * 16 + l15) * 32 + l4 * 8);
#pragma unroll
    for (int t = 0; t < 4; ++t)
      bfr[t] = *(const bf16x8*)(Bs + (wn + t * 16 + l15) * 32 + l4 * 8);
#pragma unroll
    for (int mt = 0; mt < 2; ++mt)
#pragma unroll
      for (int nt = 0; nt < 4; ++nt)
        acc[mt][nt] = __builtin_amdgcn_mfma_f32_16x16x32_bf16(af[mt], bfr[nt],
                                                              acc[mt][nt], 0, 0, 0);
  }

  __syncthreads();  // staging dead before Rt overlay
#pragma unroll
  for (int mt = 0; mt < 2; ++mt)
#pragma unroll
    for (int r = 0; r < 4; ++r) {
      const int row = wm + mt * 16 + l4 * 4 + r;
      const float inv = 1.0f / denom[b * NQ + qB + row];
#pragma unroll
      for (int nt = 0; nt < 4; ++nt)
        Rt[row * RT_LD + wn + nt * 16 + l15] = (bf16)(acc[mt][nt][r] * inv);
    }
  __syncthreads();
  const int r0 = tid >> 2, cq = (tid & 3) * 32;
#pragma unroll
  for (int j = 0; j < 4; ++j) {
    bf16x8 v = *(const bf16x8*)(Rt + r0 * RT_LD + cq + j * 8);
    *(bf16x8*)(x + (long)(b * NQ + qB + r0) * DD + dB + cq + j * 8) = v;
  }
}

extern "C" void kernel_launch(void* const* d_in, const int* in_sizes, int n_in,
                              void* d_out, int out_size, void* d_ws, size_t ws_size,
                              hipStream_t stream) {
  const float* proto = (const float*)d_in[0];
  const float* qx    = (const float*)d_in[1];
  const void*  mask  = d_in[2];
  const float* Wq    = (const float*)d_in[3];
  const float* Wk    = (const float*)d_in[4];
  const float* Wv    = (const float*)d_in[5];
  const float* Wproj = (const float*)d_in[6];
  float* out = (float*)d_out;

  char* w = (char*)d_ws;
  int*   cnt   = (int*)(w + 64);
  int*   kpadA = (int*)(w + 128);
  float* denom = (float*)(w + 4096);
  size_t off = 65536;
  bf16* Wq_b  = (bf16*)(w + off); off += (size_t)DD * DD * 2;
  bf16* Wkv_b = (bf16*)(w + off); off += (size_t)DD * DD * 4;
  bf16* Wp_b  = (bf16*)(w + off); off += (size_t)DD * DD * 2;
  int*  idx   = (int*)(w + off);  off += (size_t)NB * NKV * 4;
  bf16* q_b   = (bf16*)(w + off); off += (size_t)NB * NQ * DD * 2;   // 8MB
  bf16* k_b   = (bf16*)(w + off); off += (size_t)NB * NKV * DD * 2;  // 32MB
  bf16* vT_b  = (bf16*)(w + off); off += (size_t)NB * NKV * DD * 2;  // 32MB
  bf16* x_b   = (bf16*)(w + off); off += (size_t)NB * NQ * DD * 2;   // 8MB
  size_t off_pp = off;
  bf16* proto_b = (bf16*)(w + off); off += (size_t)NB * NQ * DD * 2;
  bf16* qc_b    = (bf16*)(w + off);
  bf16* P       = (bf16*)(w + off_pp);   // 64MB, overlays proto/qc (dead by S)

  scan_mask<<<8, 256, 0, stream>>>(mask, idx, cnt, kpadA, denom);
  prep<<<7168, 256, 0, stream>>>(qx, idx, cnt, kpadA, qc_b,
                                 proto, proto_b, Wq, Wk, Wv, Wproj,
                                 Wq_b, Wkv_b, Wp_b);

  const float scale = 0.04419417382415922f;  // 512^-0.5

  // q = proto @ Wq^T  (128x128 tiles, grid (4,64))
  gemm_bt<0><<<dim3(4, 64, 1), 256, 0, stream>>>(
      proto_b, Wq_b, q_b, nullptr, DD, DD, DD, 0L, 0L, 0L,
      cnt, kpadA, nullptr, 0.f, 0);
  // k | vT = qc @ [Wk;Wv]^T  compacted rows
  gemm_bt<5><<<dim3(256, 8, 1), 256, 0, stream>>>(
      qc_b, Wkv_b, k_b, vT_b, 1024, DD, DD, 0L, 0L, 0L,
      cnt, kpadA, nullptr, 0.f, 0);
  // P = exp(scale * q @ k^T), zero cols >= cnt[b]; denom += row sums
  gemm_bt<2><<<dim3(NKV / 128, NQ / 128, NB), 256, 0, stream>>>(
      q_b, k_b, P, nullptr, NKV, DD, DD,
      (long)NQ * DD, (long)NKV * DD, (long)NQ * NKV,
      cnt, kpadA, denom, scale, NQ);
  // x = (P @ vT^T) / denom
  pv_direct<<<dim3(16, 4, 8), 256, 0, stream>>>(P, vT_b, denom, kpadA, x_b);
  // out = x @ Wproj^T  fp32
  gemm_bt<4><<<dim3(4, 64, 1), 256, 0, stream>>>(
      x_b, Wp_b, out, nullptr, DD, DD, DD, 0L, 0L, 0L,
      cnt, kpadA, nullptr, 0.f, 0);
}

// Round 7
// 310.385 us; speedup vs baseline: 2.1906x; 2.1906x over previous
//
#include <hip/hip_runtime.h>
#include <hip/hip_bf16.h>
#include <stdint.h>

// QSCrossAttention: B=8, Nq=1024, Nkv=4096, D=512, fp32 I/O, bf16 MFMA compute.
// R15: S-GEMM ported to the 256^2 8-wave counted-vmcnt phase template (T3+T4+T5,
//      m196-m201 lineage): 512 thr, per-wave 128x64 out, BK=64 as 2 k-half
//      phases, dbuf 128KB LDS, per phase {vmcnt(4); s_barrier; sched_barrier;
//      issue next chunk; 12 ds_read; 32 MFMA w/ setprio}. Chunks fly 2 phases.
//      launch_bounds(512,1): no spill possible (R14: launch_bounds(256,6)
//      spilled acc -> 276MB scratch writes, 680us). Other kernels = R13 state.

typedef __bf16 bf16;
typedef bf16 bf16x8 __attribute__((ext_vector_type(8)));
typedef bf16 bf16x4 __attribute__((ext_vector_type(4)));
typedef float f32x4 __attribute__((ext_vector_type(4)));

#define NB 8
#define NQ 1024
#define NKV 4096
#define DD 512
#define RT_LD 136   // repack leading dim for 128-col tiles
#define RT2_LD 264  // repack leading dim for 256-col tiles

// Async global->LDS, 16B per lane. g per-lane global src; l WAVE-UNIFORM base.
__device__ __forceinline__ void lds16(const bf16* g, bf16* l) {
  __builtin_amdgcn_global_load_lds(
      (const __attribute__((address_space(1))) unsigned int*)g,
      (__attribute__((address_space(3))) unsigned int*)l, 16, 0, 0);
}

// ---- scan_mask: 3-mode sniff + denom zero + per-batch prefix scan ---------
__global__ void scan_mask(const void* __restrict__ mask,
                          int* __restrict__ idx, int* __restrict__ cnt,
                          int* __restrict__ kpad, float* __restrict__ denom) {
  const int b = blockIdx.x, tid = threadIdx.x;
  for (int i = tid; i < NQ; i += 256) denom[b * NQ + i] = 0.f;

  __shared__ int s0, s1;
  if (tid == 0) { s0 = 0; s1 = 0; }
  __syncthreads();
  {
    const unsigned* mw = (const unsigned*)mask;
    int b0 = 0, b1 = 0;
    for (int i = tid; i < 8192; i += 256) {
      unsigned v = mw[i];
      if (v > 1u) b0 = 1;
      if (v != 0u && v != 0x3F800000u) b1 = 1;
    }
    if (b0) atomicOr(&s0, 1);
    if (b1) atomicOr(&s1, 1);
  }
  __syncthreads();
  const int mode = (s0 == 0) ? 0 : ((s1 == 0) ? 1 : 2);

  __shared__ int ps[256];
  unsigned bits = 0;
  int c = 0;
  const int base = tid * 16;
  for (int i = 0; i < 16; ++i) {
    const int col = base + i;
    bool k;
    if (mode == 0)      k = ((const int*)mask)[b * NKV + col] != 0;
    else if (mode == 1) k = ((const float*)mask)[b * NKV + col] != 0.f;
    else                k = ((const unsigned char*)mask)[b * NKV + col] != 0;
    bits |= (unsigned)k << i;
    c += k;
  }
  ps[tid] = c;
  __syncthreads();
  for (int s = 1; s < 256; s <<= 1) {
    int v = (tid >= s) ? ps[tid - s] : 0;
    __syncthreads();
    ps[tid] += v;
    __syncthreads();
  }
  int off = ps[tid] - c;
  for (int i = 0; i < 16; ++i)
    if ((bits >> i) & 1) idx[b * NKV + off++] = base + i;
  if (tid == 255) {
    cnt[b] = ps[255];
    kpad[b] = (ps[255] + 127) & ~127;
  }
}

// ---- prep: gather_qx (blk<2048) | cvt proto (<6144) | cvt weights ---------
__global__ void prep(const float* __restrict__ qx, const int* __restrict__ idx,
                     const int* __restrict__ cnt, const int* __restrict__ kpad,
                     bf16* __restrict__ qc,
                     const float* __restrict__ proto, bf16* __restrict__ proto_b,
                     const float* __restrict__ Wq, const float* __restrict__ Wk,
                     const float* __restrict__ Wv, const float* __restrict__ Wp,
                     bf16* __restrict__ Wq_b, bf16* __restrict__ Wkv_b,
                     bf16* __restrict__ Wp_b) {
  const int blk = blockIdx.x, tid = threadIdx.x;
  if (blk < 2048) {
    const int b = blk >> 8, bx = blk & 255;
    const int wave = tid >> 6, lane = tid & 63;
    const int r0 = bx * 16 + wave * 4;
    const int n = cnt[b];
    const int kp = kpad[b];
#pragma unroll
    for (int j = 0; j < 4; ++j) {
      const int row = r0 + j;
      if (row >= kp) return;
      bf16x4* d = (bf16x4*)(qc + ((long)b * NKV + row) * DD) + lane;
      if (row < n) {
        const int src = idx[b * NKV + row];
        const float4* s = (const float4*)(qx + ((long)b * NKV + src) * DD) + lane;
        float4 v0 = s[0], v1 = s[64];
        bf16x4 o0, o1;
        o0.x = (bf16)v0.x; o0.y = (bf16)v0.y; o0.z = (bf16)v0.z; o0.w = (bf16)v0.w;
        o1.x = (bf16)v1.x; o1.y = (bf16)v1.y; o1.z = (bf16)v1.z; o1.w = (bf16)v1.w;
        d[0] = o0;
        d[64] = o1;
      } else {
        bf16x4 z;
        z.x = (bf16)0.f; z.y = (bf16)0.f; z.z = (bf16)0.f; z.w = (bf16)0.f;
        d[0] = z;
        d[64] = z;
      }
    }
  } else if (blk < 6144) {
    const int i = (blk - 2048) * 256 + tid;
    float4 v = ((const float4*)proto)[i];
    bf16x4 o;
    o.x = (bf16)v.x; o.y = (bf16)v.y; o.z = (bf16)v.z; o.w = (bf16)v.w;
    ((bf16x4*)proto_b)[i] = o;
  } else {
    const int j = (blk - 6144) * 256 + tid;
    const int w = j >> 16, r = j & 65535;
    const float* src = (w == 0) ? Wq : (w == 1) ? Wk : (w == 2) ? Wv : Wp;
    bf16x4* dst = (w == 0) ? (bf16x4*)Wq_b
                : (w == 3) ? (bf16x4*)Wp_b
                           : (bf16x4*)Wkv_b + (w == 2 ? 65536 : 0);
    float4 v = ((const float4*)src)[r];
    bf16x4 o;
    o.x = (bf16)v.x; o.y = (bf16)v.y; o.z = (bf16)v.z; o.w = (bf16)v.w;
    dst[r] = o;
  }
}

// ---------- S-GEMM: 256x256 tile, 8 waves, counted-vmcnt phases ------------
// P = exp(scale * q @ k^T) with col<cnt zeroing; denom += rowsums.
// Grid (NKV/256, NQ/256, NB), 512 threads. LDS 128KB dbuf.
// Layout: [A0(16384) B0(16384) A1(16384) B1(16384)] elts; each operand-buf =
// 2 k-halves x 16 subtiles[16r][32k]. Per wave per chunk: 4 lds16 (A s, s+8,
// B s, s+8). Per phase: vmcnt(4) -> own chunk landed, next chunk in flight.
__global__ void __launch_bounds__(512, 1)
sgemm256(const bf16* __restrict__ A, const bf16* __restrict__ Bw,
         bf16* __restrict__ P, const int* __restrict__ cnt,
         const int* __restrict__ kpad, float* __restrict__ denom, float scale) {
  __shared__ alignas(16) bf16 Smem[65536];  // 128KB
  const int tid = threadIdx.x;
  const int wave = tid >> 6, lane = tid & 63;
  const int l15 = lane & 15, l4 = lane >> 4;
  const int wm = wave >> 2, wn = wave & 3;  // 2M x 4N wave grid
  const int bx = blockIdx.x, by = blockIdx.y, b = blockIdx.z;
  if (bx * 256 >= kpad[b]) return;

  const bf16* Ab = A + (long)b * NQ * DD + (long)(by * 256) * DD;
  const bf16* Bb = Bw + (long)b * NKV * DD + (long)(bx * 256) * DD;
  const int srow = lane >> 2, scol = (lane & 3) * 8;
  const int s0 = wave, s1 = wave + 8;
  const bf16* aG0 = Ab + (long)(s0 * 16 + srow) * DD + scol;
  const bf16* aG1 = Ab + (long)(s1 * 16 + srow) * DD + scol;
  const bf16* bG0 = Bb + (long)(s0 * 16 + srow) * DD + scol;
  const bf16* bG1 = Bb + (long)(s1 * 16 + srow) * DD + scol;
  bf16* aL0 = Smem + s0 * 512;
  bf16* aL1 = Smem + s1 * 512;
  bf16* bL0 = Smem + 16384 + s0 * 512;
  bf16* bL1 = Smem + 16384 + s1 * 512;

  f32x4 acc[8][4] = {};

  // prologue: both k-half chunks of tile 0 into buffer 0
#pragma unroll
  for (int kh = 0; kh < 2; ++kh) {
    const int o = kh * 8192;
    lds16(aG0 + kh * 32, aL0 + o);
    lds16(aG1 + kh * 32, aL1 + o);
    lds16(bG0 + kh * 32, bL0 + o);
    lds16(bG1 + kh * 32, bL1 + o);
  }

  for (int t = 0; t < 8; ++t) {
    const int d = (t & 1) * 32768;
#pragma unroll
    for (int kh = 0; kh < 2; ++kh) {
      // own chunk landed; next chunk (4 loads) may stay in flight
      if (t < 7 || kh == 0)
        asm volatile("s_waitcnt vmcnt(4)" ::: "memory");
      else
        asm volatile("s_waitcnt vmcnt(0)" ::: "memory");
      __builtin_amdgcn_s_barrier();   // all waves' chunk loads landed
      __builtin_amdgcn_sched_barrier(0);
      if (t < 7) {  // issue chunk kh of tile t+1 into the other buffer
        const int dn = (d ^ 32768) + kh * 8192;
        const long ko = (long)(t + 1) * 64 + kh * 32;
        lds16(aG0 + ko, aL0 + dn);
        lds16(aG1 + ko, aL1 + dn);
        lds16(bG0 + ko, bL0 + dn);
        lds16(bG1 + ko, bL1 + dn);
      }
      bf16x8 af[8], bfr[4];
      const bf16* Ap = Smem + d + kh * 8192 + wm * 4096 + l15 * 32 + l4 * 8;
      const bf16* Bp = Smem + d + 16384 + kh * 8192 + wn * 2048 + l15 * 32 + l4 * 8;
#pragma unroll
      for (int mt = 0; mt < 8; ++mt) af[mt] = *(const bf16x8*)(Ap + mt * 512);
#pragma unroll
      for (int nt = 0; nt < 4; ++nt) bfr[nt] = *(const bf16x8*)(Bp + nt * 512);
      __builtin_amdgcn_s_setprio(1);
#pragma unroll
      for (int mt = 0; mt < 8; ++mt)
#pragma unroll
        for (int nt = 0; nt < 4; ++nt)
          acc[mt][nt] = __builtin_amdgcn_mfma_f32_16x16x32_bf16(
              af[mt], bfr[nt], acc[mt][nt], 0, 0, 0);
      __builtin_amdgcn_s_setprio(0);
    }
  }
  __syncthreads();  // staging dead; epilogue overlay safe

  const int nkeep = cnt[b];
  const int tR = by * 256, tC = bx * 256;
  bf16* Cb = P + (long)b * NQ * NKV;

  // rowsums -> denom atomics (each wave covers 64 of 256 kv-cols of its rows)
  float rs[8][4];
#pragma unroll
  for (int mt = 0; mt < 8; ++mt)
#pragma unroll
    for (int r = 0; r < 4; ++r) rs[mt][r] = 0.f;
#pragma unroll
  for (int nt = 0; nt < 4; ++nt) {
    const bool keep = (tC + wn * 64 + nt * 16 + l15) < nkeep;
#pragma unroll
    for (int mt = 0; mt < 8; ++mt)
#pragma unroll
      for (int r = 0; r < 4; ++r)
        rs[mt][r] += keep ? __expf(acc[mt][nt][r] * scale) : 0.f;
  }
#pragma unroll
  for (int mt = 0; mt < 8; ++mt)
#pragma unroll
    for (int r = 0; r < 4; ++r) {
      float v = rs[mt][r];
      v += __shfl_xor(v, 1, 64);
      v += __shfl_xor(v, 2, 64);
      v += __shfl_xor(v, 4, 64);
      v += __shfl_xor(v, 8, 64);
      if (l15 == 0)
        atomicAdd(&denom[b * NQ + tR + wm * 128 + mt * 16 + l4 * 4 + r], v);
    }

  // P store via two 128-row Rt[128][RT2_LD] repack halves
  bf16* Rt = Smem;
  const int r0 = tid >> 2, cb = (tid & 3) * 64;
#pragma unroll
  for (int h = 0; h < 2; ++h) {
    if (wm == h) {
#pragma unroll
      for (int nt = 0; nt < 4; ++nt) {
        const bool keep = (tC + wn * 64 + nt * 16 + l15) < nkeep;
#pragma unroll
        for (int mt = 0; mt < 8; ++mt)
#pragma unroll
          for (int r = 0; r < 4; ++r) {
            float p = keep ? __expf(acc[mt][nt][r] * scale) : 0.f;
            Rt[(mt * 16 + l4 * 4 + r) * RT2_LD + wn * 64 + nt * 16 + l15] =
                (bf16)p;
          }
      }
    }
    __syncthreads();
#pragma unroll
    for (int j = 0; j < 8; ++j) {
      bf16x8 v = *(const bf16x8*)(Rt + r0 * RT2_LD + cb + j * 8);
      *(bf16x8*)(Cb + (long)(tR + h * 128 + r0) * NKV + tC + cb + j * 8) = v;
    }
    __syncthreads();
  }
}

// ------------- 128x128-tile GEMM, BK=32, depth-3 counted-vmcnt -------------
// (R13 state) EPI 0 = bf16 store (q-proj). EPI 4 = f32 store (out-proj).
// EPI 5 = kv dual (k | vT transposed).
template <int EPI>
__global__ void __launch_bounds__(256, 3)
gemm_bt(const bf16* __restrict__ A, const bf16* __restrict__ Bw,
        void* __restrict__ Cp, void* __restrict__ Cp2,
        int N, int Klen, int Kstride,
        long sA, long sB, long sC,
        const int* __restrict__ cnt, const int* __restrict__ kpad,
        float* __restrict__ denom, float scale, int M) {
  __shared__ alignas(16) bf16 Smem[24576];  // 48KB: 3 x [A(4096) B(4096)]
  bf16* Rt = Smem;
  const int tid = threadIdx.x;
  const int wave = tid >> 6, lane = tid & 63;
  const int l15 = lane & 15, l4 = lane >> 4;
  const int wm = (wave >> 1) * 64, wn = (wave & 1) * 64;
  const int bx = (EPI == 5) ? blockIdx.y : blockIdx.x;
  const int by = (EPI == 5) ? blockIdx.x : blockIdx.y;
  const int b = blockIdx.z;

  if constexpr (EPI == 5) {
    const int bb = by >> 5, loc = (by & 31) * 128;
    if (loc >= kpad[bb]) return;
  }

  const bf16* Ab = A + (long)b * sA + (long)(by * 128) * Kstride;
  const bf16* Bb = Bw + (long)b * sB + (long)(bx * 128) * Kstride;

  const int srow = lane >> 2, scol = (lane & 3) * 8;
  const int c0 = wave * 2, c1 = wave * 2 + 1;
  const bf16* g0 = Ab + (long)(c0 * 16 + srow) * Kstride + scol;
  const bf16* g1 = Ab + (long)(c1 * 16 + srow) * Kstride + scol;
  const bf16* g2 = Bb + (long)(c0 * 16 + srow) * Kstride + scol;
  const bf16* g3 = Bb + (long)(c1 * 16 + srow) * Kstride + scol;
  bf16* l0 = Smem + c0 * 512;
  bf16* l1 = Smem + c1 * 512;
  bf16* l2 = Smem + 4096 + c0 * 512;
  bf16* l3 = Smem + 4096 + c1 * 512;

  f32x4 acc[4][4] = {};
  const int nt = Klen >> 5;

#define GSTAGE(bb)                                            \
  do {                                                        \
    const int o_ = (bb) * 8192;                               \
    lds16(g0, l0 + o_); lds16(g1, l1 + o_);                   \
    lds16(g2, l2 + o_); lds16(g3, l3 + o_);                   \
    g0 += 32; g1 += 32; g2 += 32; g3 += 32;                   \
  } while (0)

  GSTAGE(0);
  GSTAGE(1);
  int rd = 0, wr = 2;
  for (int t = 0; t < nt; ++t) {
    if (t + 1 < nt) {
      asm volatile("s_waitcnt vmcnt(4)" ::: "memory");
    } else {
      asm volatile("s_waitcnt vmcnt(0)" ::: "memory");
    }
    __builtin_amdgcn_s_barrier();
    __builtin_amdgcn_sched_barrier(0);
    if (t + 2 < nt) GSTAGE(wr);
    wr = (wr == 2) ? 0 : wr + 1;
    const bf16* Ac = Smem + rd * 8192;
    const bf16* Bc = Ac + 4096;
    rd = (rd == 2) ? 0 : rd + 1;
    bf16x8 af[4], bfr[4];
#pragma unroll
    for (int t2 = 0; t2 < 4; ++t2) {
      af[t2]  = *(const bf16x8*)(Ac + (wm + t2 * 16 + l15) * 32 + l4 * 8);
      bfr[t2] = *(const bf16x8*)(Bc + (wn + t2 * 16 + l15) * 32 + l4 * 8);
    }
#pragma unroll
    for (int mt = 0; mt < 4; ++mt)
#pragma unroll
      for (int nt2 = 0; nt2 < 4; ++nt2)
        acc[mt][nt2] = __builtin_amdgcn_mfma_f32_16x16x32_bf16(af[mt], bfr[nt2],
                                                               acc[mt][nt2], 0, 0, 0);
  }
#undef GSTAGE
  __syncthreads();

  const int tR = by * 128;
  const int tC = bx * 128;

  if constexpr (EPI == 0) {
    bf16* C = (bf16*)Cp;
#pragma unroll
    for (int mt = 0; mt < 4; ++mt)
#pragma unroll
      for (int nt2 = 0; nt2 < 4; ++nt2)
#pragma unroll
        for (int r = 0; r < 4; ++r)
          Rt[(wm + mt * 16 + l4 * 4 + r) * RT_LD + wn + nt2 * 16 + l15] =
              (bf16)acc[mt][nt2][r];
    __syncthreads();
    const int r0 = tid >> 2, cq = (tid & 3) * 32;
#pragma unroll
    for (int h = 0; h < 128; h += 64)
#pragma unroll
      for (int j = 0; j < 4; ++j) {
        bf16x8 v = *(const bf16x8*)(Rt + (r0 + h) * RT_LD + cq + j * 8);
        *(bf16x8*)(C + (long)(tR + r0 + h) * N + tC + cq + j * 8) = v;
      }
  } else if constexpr (EPI == 4) {
    float* C = (float*)Cp;
#pragma unroll
    for (int mt = 0; mt < 4; ++mt)
#pragma unroll
      for (int nt2 = 0; nt2 < 4; ++nt2)
#pragma unroll
        for (int r = 0; r < 4; ++r)
          C[(long)(tR + wm + mt * 16 + l4 * 4 + r) * N + tC + wn + nt2 * 16 + l15] =
              acc[mt][nt2][r];
  } else {  // EPI == 5
    if (tC < 512) {
      bf16* C = (bf16*)Cp;  // k: [B*NKV][512]
#pragma unroll
      for (int mt = 0; mt < 4; ++mt)
#pragma unroll
        for (int nt2 = 0; nt2 < 4; ++nt2)
#pragma unroll
          for (int r = 0; r < 4; ++r)
            Rt[(wm + mt * 16 + l4 * 4 + r) * RT_LD + wn + nt2 * 16 + l15] =
                (bf16)acc[mt][nt2][r];
      __syncthreads();
      const int r0 = tid >> 2, cq = (tid & 3) * 32;
#pragma unroll
      for (int h = 0; h < 128; h += 64)
#pragma unroll
        for (int j = 0; j < 4; ++j) {
          bf16x8 v = *(const bf16x8*)(Rt + (r0 + h) * RT_LD + cq + j * 8);
          *(bf16x8*)(C + (long)(tR + r0 + h) * 512 + tC + cq + j * 8) = v;
        }
    } else {
      bf16* C = (bf16*)Cp2;  // vT: [B][512][NKV]
#pragma unroll
      for (int mt = 0; mt < 4; ++mt) {
        const int r0 = wm + mt * 16 + l4 * 4;
#pragma unroll
        for (int nt2 = 0; nt2 < 4; ++nt2) {
          const int cloc = wn + nt2 * 16 + l15;
          bf16x4 o;
          o.x = (bf16)acc[mt][nt2][0]; o.y = (bf16)acc[mt][nt2][1];
          o.z = (bf16)acc[mt][nt2][2]; o.w = (bf16)acc[mt][nt2][3];
          *(bf16x4*)(Rt + cloc * RT_LD + r0) = o;
        }
      }
      __syncthreads();
      const int bb = tR >> 12, kvloc = tR & 4095;
      const int d0 = tid >> 2, kvq = (tid & 3) * 32;
#pragma unroll
      for (int h = 0; h < 128; h += 64)
#pragma unroll
        for (int j = 0; j < 4; ++j) {
          bf16x8 v = *(const bf16x8*)(Rt + (d0 + h) * RT_LD + kvq + j * 8);
          *(bf16x8*)(C + (long)bb * DD * NKV + (long)(tC - 512 + d0 + h) * NKV +
                     kvloc + kvq + j * 8) = v;
        }
    }
  }
}

// ------ PV direct: x = (P @ vT^T)/denom, BK=32, depth-3 counted-vmcnt ------
__global__ void __launch_bounds__(256, 4)
pv_direct(const bf16* __restrict__ P, const bf16* __restrict__ vT,
          const float* __restrict__ denom, const int* __restrict__ kpad,
          bf16* __restrict__ x) {
  __shared__ alignas(16) bf16 Smem[18432];  // 36KB
  bf16* Rt = Smem;
  const int tid = threadIdx.x;
  const int wave = tid >> 6, lane = tid & 63;
  const int l15 = lane & 15, l4 = lane >> 4;
  const int wm = (wave >> 1) * 32, wn = (wave & 1) * 64;
  const int qB = blockIdx.x * 64;
  const int dB = blockIdx.y * 128;
  const int b = blockIdx.z;
  const int Kb = kpad[b];

  const bf16* Ab = P + (long)b * NQ * NKV + (long)qB * NKV;
  const bf16* Bb = vT + (long)b * DD * NKV + (long)dB * NKV;

  const int srow = lane >> 2, scol = (lane & 3) * 8;
  const int c0 = wave * 2, c1 = wave * 2 + 1;
  const bf16* ga  = Ab + (long)(wave * 16 + srow) * NKV + scol;
  const bf16* gb0 = Bb + (long)(c0 * 16 + srow) * NKV + scol;
  const bf16* gb1 = Bb + (long)(c1 * 16 + srow) * NKV + scol;
  bf16* la  = Smem + wave * 512;
  bf16* lb0 = Smem + 2048 + c0 * 512;
  bf16* lb1 = Smem + 2048 + c1 * 512;

  f32x4 acc[2][4] = {};
  const int nt = Kb >> 5;

#define PSTAGE(bb)                                           \
  do {                                                       \
    const int o_ = (bb) * 6144;                              \
    lds16(ga, la + o_); lds16(gb0, lb0 + o_);                \
    lds16(gb1, lb1 + o_);                                    \
    ga += 32; gb0 += 32; gb1 += 32;                          \
  } while (0)

  PSTAGE(0);
  PSTAGE(1);
  int rd = 0, wr = 2;
  for (int t = 0; t < nt; ++t) {
    if (t + 1 < nt) {
      asm volatile("s_waitcnt vmcnt(3)" ::: "memory");
    } else {
      asm volatile("s_waitcnt vmcnt(0)" ::: "memory");
    }
    __builtin_amdgcn_s_barrier();
    __builtin_amdgcn_sched_barrier(0);
    if (t + 2 < nt) PSTAGE(wr);
    wr = (wr == 2) ? 0 : wr + 1;
    const bf16* Ac = Smem + rd * 6144;
    const bf16* Bc = Ac + 2048;
    rd = (rd == 2) ? 0 : rd + 1;
    bf16x8 af[2], bfr[4];
#pragma unroll
    for (int t2 = 0; t2 < 2; ++t2)
      af[t2] = *(const bf16x8*)(Ac + (wm + t2 * 16 + l15) * 32 + l4 * 8);
#pragma unroll
    for (int t2 = 0; t2 < 4; ++t2)
      bfr[t2] = *(const bf16x8*)(Bc + (wn + t2 * 16 + l15) * 32 + l4 * 8);
#pragma unroll
    for (int mt = 0; mt < 2; ++mt)
#pragma unroll
      for (int nt2 = 0; nt2 < 4; ++nt2)
        acc[mt][nt2] = __builtin_amdgcn_mfma_f32_16x16x32_bf16(af[mt], bfr[nt2],
                                                               acc[mt][nt2], 0, 0, 0);
  }
#undef PSTAGE
  __syncthreads();

#pragma unroll
  for (int mt = 0; mt < 2; ++mt)
#pragma unroll
    for (int r = 0; r < 4; ++r) {
      const int row = wm + mt * 16 + l4 * 4 + r;
      const float inv = 1.0f / denom[b * NQ + qB + row];
#pragma unroll
      for (int nt2 = 0; nt2 < 4; ++nt2)
        Rt[row * RT_LD + wn + nt2 * 16 + l15] = (bf16)(acc[mt][nt2][r] * inv);
    }
  __syncthreads();
  const int r0 = tid >> 2, cq = (tid & 3) * 32;
#pragma unroll
  for (int j = 0; j < 4; ++j) {
    bf16x8 v = *(const bf16x8*)(Rt + r0 * RT_LD + cq + j * 8);
    *(bf16x8*)(x + (long)(b * NQ + qB + r0) * DD + dB + cq + j * 8) = v;
  }
}

extern "C" void kernel_launch(void* const* d_in, const int* in_sizes, int n_in,
                              void* d_out, int out_size, void* d_ws, size_t ws_size,
                              hipStream_t stream) {
  const float* proto = (const float*)d_in[0];
  const float* qx    = (const float*)d_in[1];
  const void*  mask  = d_in[2];
  const float* Wq    = (const float*)d_in[3];
  const float* Wk    = (const float*)d_in[4];
  const float* Wv    = (const float*)d_in[5];
  const float* Wproj = (const float*)d_in[6];
  float* out = (float*)d_out;

  char* w = (char*)d_ws;
  int*   cnt   = (int*)(w + 64);
  int*   kpadA = (int*)(w + 128);
  float* denom = (float*)(w + 4096);
  size_t off = 65536;
  bf16* Wq_b  = (bf16*)(w + off); off += (size_t)DD * DD * 2;
  bf16* Wkv_b = (bf16*)(w + off); off += (size_t)DD * DD * 4;
  bf16* Wp_b  = (bf16*)(w + off); off += (size_t)DD * DD * 2;
  int*  idx   = (int*)(w + off);  off += (size_t)NB * NKV * 4;
  bf16* q_b   = (bf16*)(w + off); off += (size_t)NB * NQ * DD * 2;   // 8MB
  bf16* k_b   = (bf16*)(w + off); off += (size_t)NB * NKV * DD * 2;  // 32MB
  bf16* vT_b  = (bf16*)(w + off); off += (size_t)NB * NKV * DD * 2;  // 32MB
  bf16* x_b   = (bf16*)(w + off); off += (size_t)NB * NQ * DD * 2;   // 8MB
  size_t off_pp = off;
  bf16* proto_b = (bf16*)(w + off); off += (size_t)NB * NQ * DD * 2;
  bf16* qc_b    = (bf16*)(w + off);
  bf16* P       = (bf16*)(w + off_pp);   // 64MB, overlays proto/qc (dead by S)

  scan_mask<<<8, 256, 0, stream>>>(mask, idx, cnt, kpadA, denom);
  prep<<<7168, 256, 0, stream>>>(qx, idx, cnt, kpadA, qc_b,
                                 proto, proto_b, Wq, Wk, Wv, Wproj,
                                 Wq_b, Wkv_b, Wp_b);

  const float scale = 0.04419417382415922f;  // 512^-0.5

  // q = proto @ Wq^T  (128x128 tiles, grid (4,64))
  gemm_bt<0><<<dim3(4, 64, 1), 256, 0, stream>>>(
      proto_b, Wq_b, q_b, nullptr, DD, DD, DD, 0L, 0L, 0L,
      cnt, kpadA, nullptr, 0.f, 0);
  // k | vT = qc @ [Wk;Wv]^T  compacted rows
  gemm_bt<5><<<dim3(256, 8, 1), 256, 0, stream>>>(
      qc_b, Wkv_b, k_b, vT_b, 1024, DD, DD, 0L, 0L, 0L,
      cnt, kpadA, nullptr, 0.f, 0);
  // P = exp(scale * q @ k^T): 256^2 counted-vmcnt template
  sgemm256<<<dim3(NKV / 256, NQ / 256, NB), 512, 0, stream>>>(
      q_b, k_b, P, cnt, kpadA, denom, scale);
  // x = (P @ vT^T) / denom
  pv_direct<<<dim3(16, 4, 8), 256, 0, stream>>>(P, vT_b, denom, kpadA, x_b);
  // out = x @ Wproj^T  fp32
  gemm_bt<4><<<dim3(4, 64, 1), 256, 0, stream>>>(
      x_b, Wp_b, out, nullptr, DD, DD, DD, 0L, 0L, 0L,
      cnt, kpadA, nullptr, 0.f, 0);
}